// Round 5
// baseline (366.317 us; speedup 1.0000x reference)
//
#include <hip/hip_runtime.h>
#include <hip/hip_bf16.h>
#include <math.h>

// Problem constants (from reference setup_inputs)
#define BB   32
#define TT_  8192
#define QD   512
#define VD   256
#define DD   128
#define TINYF 1.17549435e-38f

#define CCH  32    // c-chunk for the score GEMM

// Speculation window. At TSPEC=512 the "no fp32 underflow of cumprod" event
// is ~4.6 sigma => fallback effectively never taken (R1 empirically all-fast).
// Fallback stays as PARALLEL guarded kernels (earlier lesson: an in-block
// single-CU fallback cost 3.6 ms when taken).
#define TSPEC 512

// ---------------- Kernel 0: q projection (hoisted, once per b) --------------
// qws[b][d] = (query[b] @ Wq)[d] + bq[d] + bv[d]
// Identical arithmetic order to the old in-block version -> bitwise-identical.
__global__ __launch_bounds__(256) void k_qproj(
    const float* __restrict__ query, const float* __restrict__ Wq,
    const float* __restrict__ bq, const float* __restrict__ bv,
    float* __restrict__ qws) {
  int b = blockIdx.x, tid = threadIdx.x;
  __shared__ float qrow[QD];
  __shared__ float qpart[2][DD];
  qrow[tid]       = query[b * QD + tid];
  qrow[tid + 256] = query[b * QD + tid + 256];
  __syncthreads();
  int h = tid >> 7, d = tid & 127;
  const float* wq = Wq + (size_t)(h * 256) * DD + d;
  const float* qr = qrow + h * 256;
  float qa = 0.f;
  #pragma unroll 8
  for (int c = 0; c < 256; ++c) qa = fmaf(qr[c], wq[(size_t)c * DD], qa);
  qpart[h][d] = qa;
  __syncthreads();
  if (tid < DD)
    qws[b * DD + tid] = qpart[0][tid] + qpart[1][tid] + bq[tid] + bv[tid];
}

// ---------------- Kernel 1: scores (q read from qws) ------------------------
// score[b][t] = sum_d attv[d]*tanh(qws[b][d] + (value[b][t]@Wv)[d]) + sbias
// grid: (tiles, B); flags!=null -> early-exit when flags[b]==0.
// TROWS=32 for the window launch (2 blocks/CU -> 2 waves/SIMD latency hiding);
// TROWS=64 for the guarded fallback launch (fewer early-exit blocks).
template<int TROWS>
__global__ __launch_bounds__(256) void k_score(
    const float* __restrict__ value, const float* __restrict__ qws,
    const float* __restrict__ Wv,
    const float* __restrict__ attv, const float* __restrict__ sbias,
    float* __restrict__ score, int t_base, const int* __restrict__ flags) {
  constexpr int RPG  = TROWS / 8;          // rows per 32-lane t-group (4 or 8)
  constexpr int NV4  = (TROWS * 8) / 256;  // float4 value loads per thread
  constexpr int VSTR = TROWS + 4;          // valT row stride (pad vs banks)
  int b = blockIdx.y;
  if (flags && flags[b] == 0) return;
  int tid = threadIdx.x;

  int t0 = t_base + blockIdx.x * TROWS;
  int dq = tid & 31;   // d-group of 4
  int tq = tid >> 5;   // t-group of RPG rows

  // q fragment + attv fragment loaded up-front (L2-hot; latency hidden by GEMM)
  float sb = sbias[0];
  float qd[4], av[4];
  #pragma unroll
  for (int j = 0; j < 4; ++j) {
    int d = dq * 4 + j;
    qd[j] = qws[b * DD + d];
    av[j] = attv[d];
  }

  // ---- register-tiled GEMM: (value tile) @ Wv ----
  __shared__ float WvL[CCH * DD];
  __shared__ float valT[CCH * VSTR];

  float acc[RPG][4];
  #pragma unroll
  for (int i = 0; i < RPG; ++i)
    #pragma unroll
    for (int j = 0; j < 4; ++j) acc[i][j] = 0.f;

  const float* vbase = value + ((size_t)b * TT_ + t0) * VD;

  for (int c0 = 0; c0 < VD; c0 += CCH) {
    const float4* wsrc = (const float4*)(Wv + (size_t)c0 * DD);
    float4* wdst = (float4*)WvL;
    #pragma unroll
    for (int k = 0; k < 4; ++k) wdst[tid + 256 * k] = wsrc[tid + 256 * k];
    #pragma unroll
    for (int k = 0; k < NV4; ++k) {
      int id = tid * NV4 + k;
      int tt = id >> 3;
      int c4 = id & 7;
      float4 vv = *(const float4*)(vbase + (size_t)tt * VD + c0 + c4 * 4);
      int cr = c4 * 4;
      valT[(cr + 0) * VSTR + tt] = vv.x;
      valT[(cr + 1) * VSTR + tt] = vv.y;
      valT[(cr + 2) * VSTR + tt] = vv.z;
      valT[(cr + 3) * VSTR + tt] = vv.w;
    }
    __syncthreads();
    #pragma unroll 4
    for (int cc = 0; cc < CCH; ++cc) {
      const float4 wv  = *(const float4*)(&WvL[cc * DD + dq * 4]);
      float va[RPG];
      const float4 va0 = *(const float4*)(&valT[cc * VSTR + tq * RPG]);
      va[0] = va0.x; va[1] = va0.y; va[2] = va0.z; va[3] = va0.w;
      if constexpr (RPG == 8) {
        const float4 va1 = *(const float4*)(&valT[cc * VSTR + tq * RPG + 4]);
        va[4] = va1.x; va[5] = va1.y; va[6] = va1.z; va[7] = va1.w;
      }
      #pragma unroll
      for (int i = 0; i < RPG; ++i) {
        acc[i][0] = fmaf(va[i], wv.x, acc[i][0]);
        acc[i][1] = fmaf(va[i], wv.y, acc[i][1]);
        acc[i][2] = fmaf(va[i], wv.z, acc[i][2]);
        acc[i][3] = fmaf(va[i], wv.w, acc[i][3]);
      }
    }
    __syncthreads();
  }

  #pragma unroll
  for (int i = 0; i < RPG; ++i) {
    float s = 0.f;
    #pragma unroll
    for (int j = 0; j < 4; ++j) {
      float x = qd[j] + acc[i][j];
      s += av[j] * tanhf(x);
    }
    #pragma unroll
    for (int m = 16; m >= 1; m >>= 1) s += __shfl_xor(s, m, 64);
    if (dq == 0) score[(size_t)b * TT_ + t0 + tq * RPG + i] = s + sb;
  }
}

// ------- Kernel 2: fused window scan + tail-zero + u + ctx ------------------
// R1-VERIFIED 512-thread version. Single-pass scan over the TSPEC=512 window
// (8-wave two-level scan), u split 2-way across t, ctx split 2-way across VD.
// Fast path (cumprod underflowed by TSPEC): completes everything for b.
// Else: stores carries + window-u, sets flags[b]=1 for the fallback chain.
__global__ __launch_bounds__(512) void k_fused(
    const float* __restrict__ score, const float* __restrict__ prev,
    const float* __restrict__ value, const float* __restrict__ Wv,
    const float* __restrict__ bv,
    float* __restrict__ align_out, float* __restrict__ ctx,
    float* __restrict__ suma, float* __restrict__ carryL,
    float* __restrict__ carryD, float* __restrict__ uws,
    int* __restrict__ flags) {
  int b = blockIdx.x, tid = threadIdx.x;
  int lane = tid & 63, w = tid >> 6;          // 8 waves
  __shared__ float wsA[8], wsB[8], wsS[8];
  __shared__ float aL[TSPEC];
  __shared__ float uhalf[512];
  __shared__ float uL[VD];
  __shared__ float cpart[256];
  const size_t base = (size_t)b * TT_;

  // ---- single-pass scan over t = 0..511 ----
  float s = score[base + tid];
  float p  = 1.f / (1.f + expf(-s));      // sigmoid
  float om = 1.f / (1.f + expf(s));       // 1-p without cancellation
  float l = logf(fmaxf(om, TINYF));       // log(clip(1-p, TINY, 1))

  float inc = l;
  #pragma unroll
  for (int o = 1; o < 64; o <<= 1) {
    float n = __shfl_up(inc, o, 64);
    if (lane >= o) inc += n;
  }
  if (lane == 63) wsA[w] = inc;
  __syncthreads();
  float off = 0.f, totA = 0.f;
  #pragma unroll
  for (int j = 0; j < 8; ++j) { float x = wsA[j]; totA += x; if (j < w) off += x; }
  float cp = expf(off + inc - l);         // exclusive cumprod of (1-p)
  float den = prev[base + tid] / fminf(fmaxf(cp, 1e-10f), 1.f);

  float inc2 = den;
  #pragma unroll
  for (int o = 1; o < 64; o <<= 1) {
    float n = __shfl_up(inc2, o, 64);
    if (lane >= o) inc2 += n;
  }
  if (lane == 63) wsB[w] = inc2;
  __syncthreads();
  float off2 = 0.f, totB = 0.f;
  #pragma unroll
  for (int j = 0; j < 8; ++j) { float x = wsB[j]; totB += x; if (j < w) off2 += x; }

  float a = p * cp * (off2 + inc2);
  align_out[base + tid] = a;
  aL[tid] = a;

  // ---- sum(alignment) reduce (512 threads, one element each) ----
  float sacc = a;
  #pragma unroll
  for (int o = 32; o >= 1; o >>= 1) sacc += __shfl_xor(sacc, o, 64);
  if (lane == 0) wsS[w] = sacc;
  __syncthreads();   // also publishes aL for the u-loop
  float stot = 0.f;
  #pragma unroll
  for (int j = 0; j < 8; ++j) stot += wsS[j];

  // ---- u[c] = sum_t a[t]*value[b][t][c], split 2-way across t ----
  int c = tid & (VD - 1);
  int half = tid >> 8;
  const float* vp = value + (base + (size_t)half * 256) * VD + c;
  const float* ap = aL + half * 256;
  float uacc = 0.f;
  #pragma unroll 8
  for (int tt = 0; tt < 256; ++tt) uacc = fmaf(ap[tt], vp[(size_t)tt * VD], uacc);
  uhalf[tid] = uacc;
  __syncthreads();
  if (tid < VD) uL[tid] = uhalf[tid] + uhalf[tid + VD];
  __syncthreads();

  // Block-uniform decision, forced scalar so barriers stay outside divergence.
  int fb = __builtin_amdgcn_readfirstlane((expf(totA) != 0.f) ? 1 : 0);

  if (fb) {
    // fallback chain finishes this b; save state
    if (tid == 0) { flags[b] = 1; suma[b] = stot; carryL[b] = totA; carryD[b] = totB; }
    if (tid < VD) uws[b * VD + tid] = uL[tid];  // window part of u
  } else {
    if (tid == 0) flags[b] = 0;
    // zero-fill alignment tail
    float4 z = make_float4(0.f, 0.f, 0.f, 0.f);
    float4* dst = (float4*)(align_out + base + TSPEC);
    for (int i = tid; i < (TT_ - TSPEC) / 4; i += 512) dst[i] = z;
  }

  // ctx = u @ Wv + sum(a)*bv, 2-way split across the VD reduction
  if (!fb && tid < 256) {
    int d = tid & 127, h = tid >> 7;
    float cval = (h == 0) ? stot * bv[d] : 0.f;
    const float* wp = Wv + (size_t)(h * 128) * DD + d;
    const float* up = uL + h * 128;
    #pragma unroll 8
    for (int cc = 0; cc < 128; ++cc) cval = fmaf(up[cc], wp[(size_t)cc * DD], cval);
    cpart[tid] = cval;
  }
  __syncthreads();
  if (!fb && tid < DD) ctx[b * DD + tid] = cpart[tid] + cpart[tid + 128];
}

// ------- Kernel 3: fallback tail — scan + u + ctx in one pass ---------------
// Early-exits when flags[b]==0 (the ~always case at TSPEC=512).
__global__ __launch_bounds__(256) void k_tail_fb(
    const float* __restrict__ score, const float* __restrict__ prev,
    const float* __restrict__ value, const float* __restrict__ Wv,
    const float* __restrict__ bv, const float* __restrict__ suma_in,
    const float* __restrict__ carryL, const float* __restrict__ carryD,
    const float* __restrict__ uws,
    float* __restrict__ align_out, float* __restrict__ ctx,
    const int* __restrict__ flags) {
  int b = blockIdx.x, tid = threadIdx.x;
  if (flags[b] == 0) return;
  int lane = tid & 63, w = tid >> 6;
  __shared__ float wsA[4], wsB[4];
  __shared__ float aL[256];
  __shared__ float uL[256];
  __shared__ int any;
  float cL = carryL[b], cD = carryD[b];
  float sacc = (tid == 0) ? suma_in[b] : 0.f;   // window sum, counted ONCE
  float uacc = uws[b * VD + tid];               // window part of u (c = tid)
  const size_t base = (size_t)b * TT_;

  for (int ch = TSPEC / 256; ch < TT_ / 256; ++ch) {
    int t = ch * 256 + tid;
    float s = score[base + t];
    float p  = 1.f / (1.f + expf(-s));
    float om = 1.f / (1.f + expf(s));
    float l = logf(fmaxf(om, TINYF));

    float inc = l;
    #pragma unroll
    for (int o = 1; o < 64; o <<= 1) {
      float n = __shfl_up(inc, o, 64);
      if (lane >= o) inc += n;
    }
    if (lane == 63) wsA[w] = inc;
    if (tid == 0) any = 0;
    __syncthreads();
    float off = 0.f;
    #pragma unroll
    for (int j = 0; j < 4; ++j) if (j < w) off += wsA[j];
    float totA = wsA[0] + wsA[1] + wsA[2] + wsA[3];
    float cp = expf(cL + off + inc - l);
    float den = prev[base + t] / fminf(fmaxf(cp, 1e-10f), 1.f);

    float inc2 = den;
    #pragma unroll
    for (int o = 1; o < 64; o <<= 1) {
      float n = __shfl_up(inc2, o, 64);
      if (lane >= o) inc2 += n;
    }
    if (lane == 63) wsB[w] = inc2;
    __syncthreads();
    float off2 = 0.f;
    #pragma unroll
    for (int j = 0; j < 4; ++j) if (j < w) off2 += wsB[j];
    float totB = wsB[0] + wsB[1] + wsB[2] + wsB[3];

    float a = p * cp * (cD + off2 + inc2);
    align_out[base + t] = a;
    sacc += a;
    aL[tid] = a;
    if (a != 0.f) any = 1;  // benign same-value race
    __syncthreads();

    if (any) {
      const float* vp = value + (base + (size_t)ch * 256) * VD + tid;
      #pragma unroll 8
      for (int tt = 0; tt < 256; ++tt) uacc = fmaf(aL[tt], vp[(size_t)tt * VD], uacc);
    }
    cL += totA; cD += totB;
    __syncthreads();   // protect wsA/wsB/aL before next chunk
  }

  // ---- final sum(alignment) reduce ----
  #pragma unroll
  for (int o = 32; o >= 1; o >>= 1) sacc += __shfl_xor(sacc, o, 64);
  if (lane == 0) wsA[w] = sacc;
  __syncthreads();
  float stot = wsA[0] + wsA[1] + wsA[2] + wsA[3];

  uL[tid] = uacc;
  __syncthreads();
  if (tid < DD) {
    float c = stot * bv[tid];
    #pragma unroll 8
    for (int cc = 0; cc < VD; ++cc) c = fmaf(uL[cc], Wv[cc * DD + tid], c);
    ctx[b * DD + tid] = c;
  }
}

extern "C" void kernel_launch(void* const* d_in, const int* in_sizes, int n_in,
                              void* d_out, int out_size, void* d_ws, size_t ws_size,
                              hipStream_t stream) {
  const float* query = (const float*)d_in[0];
  const float* value = (const float*)d_in[1];
  const float* prev  = (const float*)d_in[2];
  const float* Wq    = (const float*)d_in[3];
  const float* bq    = (const float*)d_in[4];
  const float* Wv    = (const float*)d_in[5];
  const float* bv    = (const float*)d_in[6];
  const float* attv  = (const float*)d_in[7];
  const float* sbias = (const float*)d_in[8];

  float* ctx_out   = (float*)d_out;                 // [32][128]
  float* align_out = (float*)d_out + BB * DD;       // [32][8192]

  float* ws = (float*)d_ws;
  float* score  = ws;                  // 262144
  float* suma   = ws + 262144;         // 32
  float* carryL = ws + 262176;         // 32
  float* carryD = ws + 262208;         // 32
  int*   flags  = (int*)(ws + 262240); // 32
  float* uws    = ws + 262272;         // 8192
  float* qws    = ws + 270464;         // 4096 (q@Wq + bq + bv, [32][128])

  // node 0: q projection, once per b (replaces per-block recompute: saves
  // 512 blocks x 256 KB = 128 MB of L2 Wq traffic on the window launch)
  k_qproj<<<BB, 256, 0, stream>>>(query, Wq, bq, bv, qws);

  // node 1: speculative window scores, t < TSPEC (512 blocks, 2/CU)
  k_score<32><<<dim3(TSPEC / 32, BB), 256, 0, stream>>>(
      value, qws, Wv, attv, sbias, score, 0, nullptr);

  // node 2: window scan + tail-zero + u + ctx (fast path completes all)
  k_fused<<<BB, 512, 0, stream>>>(score, prev, value, Wv, bv, align_out,
                                  ctx_out, suma, carryL, carryD, uws, flags);

  // nodes 3-4: fallback chain, per-b early-exit (near-free when unflagged)
  k_score<64><<<dim3((TT_ - TSPEC) / 64, BB), 256, 0, stream>>>(
      value, qws, Wv, attv, sbias, score, TSPEC, flags);
  k_tail_fb<<<BB, 256, 0, stream>>>(score, prev, value, Wv, bv, suma,
                                    carryL, carryD, uws, align_out, ctx_out,
                                    flags);
}

// Round 6
// 361.911 us; speedup vs baseline: 1.0122x; 1.0122x over previous
//
#include <hip/hip_runtime.h>
#include <hip/hip_bf16.h>
#include <math.h>

// Problem constants (from reference setup_inputs)
#define BB   32
#define TT_  8192
#define QD   512
#define VD   256
#define DD   128
#define TINYF 1.17549435e-38f

#define CCH  32    // c-chunk for the score GEMM

// Speculation window. At TSPEC=512 the "no fp32 underflow of cumprod" event
// is ~4.6 sigma => fallback effectively never taken (R1 empirically all-fast).
// Fallback stays as PARALLEL guarded kernels (earlier lesson: an in-block
// single-CU fallback cost 3.6 ms when taken).
#define TSPEC 512

// ---------------- Kernel 1: scores (q recomputed in-block) ------------------
// score[b][t] = sum_d attv[d]*tanh(q[b][d]+bv[d] + (value[b][t]@Wv)[d]) + sbias
// grid: (tiles, B); flags!=null -> early-exit when flags[b]==0.
// R5 post-mortem: hoisting the q-projection to its own node was NEGATIVE
// (+2.9us) -- Wq re-reads are L2-absorbed and overlapped; the extra node adds
// serialized launch latency. In-block recompute restored (R4-verified).
// NEW this round: double-buffered c-chunk staging -- stage chunk c+1 into
// buffer^1 while computing chunk c; ONE barrier per chunk instead of two.
// FMA order over chunks unchanged -> bitwise-identical scores.
template<int TROWS>
__global__ __launch_bounds__(256) void k_score(
    const float* __restrict__ value, const float* __restrict__ query,
    const float* __restrict__ Wq, const float* __restrict__ bq,
    const float* __restrict__ Wv, const float* __restrict__ bv,
    const float* __restrict__ attv, const float* __restrict__ sbias,
    float* __restrict__ score, int t_base, const int* __restrict__ flags) {
  constexpr int RPG  = TROWS / 8;          // rows per 32-lane t-group (4 or 8)
  constexpr int NV4  = (TROWS * 8) / 256;  // float4 value loads per thread
  constexpr int VSTR = TROWS + 4;          // valT row stride (pad vs banks)
  int b = blockIdx.y;
  if (flags && flags[b] == 0) return;
  int tid = threadIdx.x;

  // ---- recompute q[b][:] + bq + bv into LDS (cheap: 256 FMA/thread) ----
  __shared__ float qrow[QD];
  __shared__ float qpart[2][DD];
  __shared__ float qsh[DD];
  qrow[tid]       = query[b * QD + tid];
  qrow[tid + 256] = query[b * QD + tid + 256];
  __syncthreads();
  {
    int h = tid >> 7, d = tid & 127;
    const float* wq = Wq + (size_t)(h * 256) * DD + d;
    const float* qr = qrow + h * 256;
    float qa = 0.f;
    #pragma unroll 8
    for (int c = 0; c < 256; ++c) qa = fmaf(qr[c], wq[(size_t)c * DD], qa);
    qpart[h][d] = qa;
  }
  __syncthreads();
  if (tid < DD) qsh[tid] = qpart[0][tid] + qpart[1][tid] + bq[tid] + bv[tid];
  __syncthreads();

  // ---- register-tiled GEMM: (value tile) @ Wv, double-buffered staging ----
  int t0 = t_base + blockIdx.x * TROWS;
  int dq = tid & 31;   // d-group of 4
  int tq = tid >> 5;   // t-group of RPG rows

  __shared__ float WvL[2][CCH * DD];
  __shared__ float valT[2][CCH * VSTR];

  float acc[RPG][4];
  #pragma unroll
  for (int i = 0; i < RPG; ++i)
    #pragma unroll
    for (int j = 0; j < 4; ++j) acc[i][j] = 0.f;

  const float* vbase = value + ((size_t)b * TT_ + t0) * VD;

  auto stage = [&](int buf, int c0) {
    const float4* wsrc = (const float4*)(Wv + (size_t)c0 * DD);
    float4* wdst = (float4*)(WvL[buf]);
    #pragma unroll
    for (int k = 0; k < 4; ++k) wdst[tid + 256 * k] = wsrc[tid + 256 * k];
    #pragma unroll
    for (int k = 0; k < NV4; ++k) {
      int id = tid * NV4 + k;
      int tt = id >> 3;
      int c4 = id & 7;
      float4 vv = *(const float4*)(vbase + (size_t)tt * VD + c0 + c4 * 4);
      int cr = c4 * 4;
      valT[buf][(cr + 0) * VSTR + tt] = vv.x;
      valT[buf][(cr + 1) * VSTR + tt] = vv.y;
      valT[buf][(cr + 2) * VSTR + tt] = vv.z;
      valT[buf][(cr + 3) * VSTR + tt] = vv.w;
    }
  };

  stage(0, 0);
  __syncthreads();
  constexpr int NCH = VD / CCH;      // 8 chunks
  #pragma unroll
  for (int ci = 0; ci < NCH; ++ci) {
    int cur = ci & 1;
    if (ci + 1 < NCH) stage(cur ^ 1, (ci + 1) * CCH);  // hide under compute
    #pragma unroll 4
    for (int cc = 0; cc < CCH; ++cc) {
      const float4 wv  = *(const float4*)(&WvL[cur][cc * DD + dq * 4]);
      float va[RPG];
      const float4 va0 = *(const float4*)(&valT[cur][cc * VSTR + tq * RPG]);
      va[0] = va0.x; va[1] = va0.y; va[2] = va0.z; va[3] = va0.w;
      if constexpr (RPG == 8) {
        const float4 va1 = *(const float4*)(&valT[cur][cc * VSTR + tq * RPG + 4]);
        va[4] = va1.x; va[5] = va1.y; va[6] = va1.z; va[7] = va1.w;
      }
      #pragma unroll
      for (int i = 0; i < RPG; ++i) {
        acc[i][0] = fmaf(va[i], wv.x, acc[i][0]);
        acc[i][1] = fmaf(va[i], wv.y, acc[i][1]);
        acc[i][2] = fmaf(va[i], wv.z, acc[i][2]);
        acc[i][3] = fmaf(va[i], wv.w, acc[i][3]);
      }
    }
    __syncthreads();   // buf^1 fully staged; all reads of buf done
  }

  float sb = sbias[0];
  float qd[4], av[4];
  #pragma unroll
  for (int j = 0; j < 4; ++j) {
    int d = dq * 4 + j;
    qd[j] = qsh[d];
    av[j] = attv[d];
  }
  #pragma unroll
  for (int i = 0; i < RPG; ++i) {
    float s = 0.f;
    #pragma unroll
    for (int j = 0; j < 4; ++j) {
      float x = qd[j] + acc[i][j];
      s += av[j] * tanhf(x);
    }
    #pragma unroll
    for (int m = 16; m >= 1; m >>= 1) s += __shfl_xor(s, m, 64);
    if (dq == 0) score[(size_t)b * TT_ + t0 + tq * RPG + i] = s + sb;
  }
}

// ------- Kernel 2: fused window scan + tail-zero + u + ctx ------------------
// R1/R4-VERIFIED 512-thread version. Single-pass scan over the TSPEC=512
// window (8-wave two-level scan), u split 2-way across t, ctx split 2-way
// across VD. Fast path (cumprod underflowed by TSPEC): completes everything
// for b. Else: stores carries + window-u, sets flags[b]=1 for the fallback.
__global__ __launch_bounds__(512) void k_fused(
    const float* __restrict__ score, const float* __restrict__ prev,
    const float* __restrict__ value, const float* __restrict__ Wv,
    const float* __restrict__ bv,
    float* __restrict__ align_out, float* __restrict__ ctx,
    float* __restrict__ suma, float* __restrict__ carryL,
    float* __restrict__ carryD, float* __restrict__ uws,
    int* __restrict__ flags) {
  int b = blockIdx.x, tid = threadIdx.x;
  int lane = tid & 63, w = tid >> 6;          // 8 waves
  __shared__ float wsA[8], wsB[8], wsS[8];
  __shared__ float aL[TSPEC];
  __shared__ float uhalf[512];
  __shared__ float uL[VD];
  __shared__ float cpart[256];
  const size_t base = (size_t)b * TT_;

  // ---- single-pass scan over t = 0..511 ----
  float s = score[base + tid];
  float p  = 1.f / (1.f + expf(-s));      // sigmoid
  float om = 1.f / (1.f + expf(s));       // 1-p without cancellation
  float l = logf(fmaxf(om, TINYF));       // log(clip(1-p, TINY, 1))

  float inc = l;
  #pragma unroll
  for (int o = 1; o < 64; o <<= 1) {
    float n = __shfl_up(inc, o, 64);
    if (lane >= o) inc += n;
  }
  if (lane == 63) wsA[w] = inc;
  __syncthreads();
  float off = 0.f, totA = 0.f;
  #pragma unroll
  for (int j = 0; j < 8; ++j) { float x = wsA[j]; totA += x; if (j < w) off += x; }
  float cp = expf(off + inc - l);         // exclusive cumprod of (1-p)
  float den = prev[base + tid] / fminf(fmaxf(cp, 1e-10f), 1.f);

  float inc2 = den;
  #pragma unroll
  for (int o = 1; o < 64; o <<= 1) {
    float n = __shfl_up(inc2, o, 64);
    if (lane >= o) inc2 += n;
  }
  if (lane == 63) wsB[w] = inc2;
  __syncthreads();
  float off2 = 0.f, totB = 0.f;
  #pragma unroll
  for (int j = 0; j < 8; ++j) { float x = wsB[j]; totB += x; if (j < w) off2 += x; }

  float a = p * cp * (off2 + inc2);
  align_out[base + tid] = a;
  aL[tid] = a;

  // ---- sum(alignment) reduce (512 threads, one element each) ----
  float sacc = a;
  #pragma unroll
  for (int o = 32; o >= 1; o >>= 1) sacc += __shfl_xor(sacc, o, 64);
  if (lane == 0) wsS[w] = sacc;
  __syncthreads();   // also publishes aL for the u-loop
  float stot = 0.f;
  #pragma unroll
  for (int j = 0; j < 8; ++j) stot += wsS[j];

  // ---- u[c] = sum_t a[t]*value[b][t][c], split 2-way across t ----
  int c = tid & (VD - 1);
  int half = tid >> 8;
  const float* vp = value + (base + (size_t)half * 256) * VD + c;
  const float* ap = aL + half * 256;
  float uacc = 0.f;
  #pragma unroll 8
  for (int tt = 0; tt < 256; ++tt) uacc = fmaf(ap[tt], vp[(size_t)tt * VD], uacc);
  uhalf[tid] = uacc;
  __syncthreads();
  if (tid < VD) uL[tid] = uhalf[tid] + uhalf[tid + VD];
  __syncthreads();

  // Block-uniform decision, forced scalar so barriers stay outside divergence.
  int fb = __builtin_amdgcn_readfirstlane((expf(totA) != 0.f) ? 1 : 0);

  if (fb) {
    // fallback chain finishes this b; save state
    if (tid == 0) { flags[b] = 1; suma[b] = stot; carryL[b] = totA; carryD[b] = totB; }
    if (tid < VD) uws[b * VD + tid] = uL[tid];  // window part of u
  } else {
    if (tid == 0) flags[b] = 0;
    // zero-fill alignment tail
    float4 z = make_float4(0.f, 0.f, 0.f, 0.f);
    float4* dst = (float4*)(align_out + base + TSPEC);
    for (int i = tid; i < (TT_ - TSPEC) / 4; i += 512) dst[i] = z;
  }

  // ctx = u @ Wv + sum(a)*bv, 2-way split across the VD reduction
  if (!fb && tid < 256) {
    int d = tid & 127, h = tid >> 7;
    float cval = (h == 0) ? stot * bv[d] : 0.f;
    const float* wp = Wv + (size_t)(h * 128) * DD + d;
    const float* up = uL + h * 128;
    #pragma unroll 8
    for (int cc = 0; cc < 128; ++cc) cval = fmaf(up[cc], wp[(size_t)cc * DD], cval);
    cpart[tid] = cval;
  }
  __syncthreads();
  if (!fb && tid < DD) ctx[b * DD + tid] = cpart[tid] + cpart[tid + 128];
}

// ------- Kernel 3: fallback tail — scan + u + ctx in one pass ---------------
// Early-exits when flags[b]==0 (the ~always case at TSPEC=512).
__global__ __launch_bounds__(256) void k_tail_fb(
    const float* __restrict__ score, const float* __restrict__ prev,
    const float* __restrict__ value, const float* __restrict__ Wv,
    const float* __restrict__ bv, const float* __restrict__ suma_in,
    const float* __restrict__ carryL, const float* __restrict__ carryD,
    const float* __restrict__ uws,
    float* __restrict__ align_out, float* __restrict__ ctx,
    const int* __restrict__ flags) {
  int b = blockIdx.x, tid = threadIdx.x;
  if (flags[b] == 0) return;
  int lane = tid & 63, w = tid >> 6;
  __shared__ float wsA[4], wsB[4];
  __shared__ float aL[256];
  __shared__ float uL[256];
  __shared__ int any;
  float cL = carryL[b], cD = carryD[b];
  float sacc = (tid == 0) ? suma_in[b] : 0.f;   // window sum, counted ONCE
  float uacc = uws[b * VD + tid];               // window part of u (c = tid)
  const size_t base = (size_t)b * TT_;

  for (int ch = TSPEC / 256; ch < TT_ / 256; ++ch) {
    int t = ch * 256 + tid;
    float s = score[base + t];
    float p  = 1.f / (1.f + expf(-s));
    float om = 1.f / (1.f + expf(s));
    float l = logf(fmaxf(om, TINYF));

    float inc = l;
    #pragma unroll
    for (int o = 1; o < 64; o <<= 1) {
      float n = __shfl_up(inc, o, 64);
      if (lane >= o) inc += n;
    }
    if (lane == 63) wsA[w] = inc;
    if (tid == 0) any = 0;
    __syncthreads();
    float off = 0.f;
    #pragma unroll
    for (int j = 0; j < 4; ++j) if (j < w) off += wsA[j];
    float totA = wsA[0] + wsA[1] + wsA[2] + wsA[3];
    float cp = expf(cL + off + inc - l);
    float den = prev[base + t] / fminf(fmaxf(cp, 1e-10f), 1.f);

    float inc2 = den;
    #pragma unroll
    for (int o = 1; o < 64; o <<= 1) {
      float n = __shfl_up(inc2, o, 64);
      if (lane >= o) inc2 += n;
    }
    if (lane == 63) wsB[w] = inc2;
    __syncthreads();
    float off2 = 0.f;
    #pragma unroll
    for (int j = 0; j < 4; ++j) if (j < w) off2 += wsB[j];
    float totB = wsB[0] + wsB[1] + wsB[2] + wsB[3];

    float a = p * cp * (cD + off2 + inc2);
    align_out[base + t] = a;
    sacc += a;
    aL[tid] = a;
    if (a != 0.f) any = 1;  // benign same-value race
    __syncthreads();

    if (any) {
      const float* vp = value + (base + (size_t)ch * 256) * VD + tid;
      #pragma unroll 8
      for (int tt = 0; tt < 256; ++tt) uacc = fmaf(aL[tt], vp[(size_t)tt * VD], uacc);
    }
    cL += totA; cD += totB;
    __syncthreads();   // protect wsA/wsB/aL before next chunk
  }

  // ---- final sum(alignment) reduce ----
  #pragma unroll
  for (int o = 32; o >= 1; o >>= 1) sacc += __shfl_xor(sacc, o, 64);
  if (lane == 0) wsA[w] = sacc;
  __syncthreads();
  float stot = wsA[0] + wsA[1] + wsA[2] + wsA[3];

  uL[tid] = uacc;
  __syncthreads();
  if (tid < DD) {
    float c = stot * bv[tid];
    #pragma unroll 8
    for (int cc = 0; cc < VD; ++cc) c = fmaf(uL[cc], Wv[cc * DD + tid], c);
    ctx[b * DD + tid] = c;
  }
}

extern "C" void kernel_launch(void* const* d_in, const int* in_sizes, int n_in,
                              void* d_out, int out_size, void* d_ws, size_t ws_size,
                              hipStream_t stream) {
  const float* query = (const float*)d_in[0];
  const float* value = (const float*)d_in[1];
  const float* prev  = (const float*)d_in[2];
  const float* Wq    = (const float*)d_in[3];
  const float* bq    = (const float*)d_in[4];
  const float* Wv    = (const float*)d_in[5];
  const float* bv    = (const float*)d_in[6];
  const float* attv  = (const float*)d_in[7];
  const float* sbias = (const float*)d_in[8];

  float* ctx_out   = (float*)d_out;                 // [32][128]
  float* align_out = (float*)d_out + BB * DD;       // [32][8192]

  float* ws = (float*)d_ws;
  float* score  = ws;                  // 262144
  float* suma   = ws + 262144;         // 32
  float* carryL = ws + 262176;         // 32
  float* carryD = ws + 262208;         // 32
  int*   flags  = (int*)(ws + 262240); // 32
  float* uws    = ws + 262272;         // 8192

  // node 1: speculative window scores, t < TSPEC (512 blocks, 2/CU)
  k_score<32><<<dim3(TSPEC / 32, BB), 256, 0, stream>>>(
      value, query, Wq, bq, Wv, bv, attv, sbias, score, 0, nullptr);

  // node 2: window scan + tail-zero + u + ctx (fast path completes all)
  k_fused<<<BB, 512, 0, stream>>>(score, prev, value, Wv, bv, align_out,
                                  ctx_out, suma, carryL, carryD, uws, flags);

  // nodes 3-4: fallback chain, per-b early-exit (near-free when unflagged)
  k_score<64><<<dim3((TT_ - TSPEC) / 64, BB), 256, 0, stream>>>(
      value, query, Wq, bq, Wv, bv, attv, sbias, score, TSPEC, flags);
  k_tail_fb<<<BB, 256, 0, stream>>>(score, prev, value, Wv, bv, suma,
                                    carryL, carryD, uws, align_out, ctx_out,
                                    flags);
}